// Round 1
// baseline (196.925 us; speedup 1.0000x reference)
//
#include <hip/hip_runtime.h>
#include <hip/hip_bf16.h>
#include <stdint.h>

#define BROWS 4096
#define DDIM  1024

typedef __bf16 bf16_t;
typedef __bf16 bf16x8 __attribute__((ext_vector_type(8)));
typedef float  f32x4  __attribute__((ext_vector_type(4)));
typedef unsigned int u32;

#define GEMM_BLOCKS 1024   // (4096/128)^2 tiles

// Lb bit layout (ballot-native): word w = (j>>8)*4 + (j&3), bit b = (j&255)>>2.

__device__ __forceinline__ unsigned short f2bf_bits(float f) {
    union { float f; unsigned int u; } v; v.f = f;
    unsigned int u = v.u;
    unsigned int r = (u + 0x7fffu + ((u >> 16) & 1u)) >> 16;
    return (unsigned short)r;
}

// direct global->LDS DMA, 16B per lane (m97 structure; compiler never auto-emits)
__device__ __forceinline__ void gload16(const void* g, void* l) {
    __builtin_amdgcn_global_load_lds(
        (const __attribute__((address_space(1))) u32*)g,
        (__attribute__((address_space(3))) u32*)l, 16, 0, 0);
}

// ---------------------------------------------------------------------------
// Kernel 1: prep — log(q)->bf16, p->bf16, e[row], kl_div[row], zero CS/CL/EL,
//   ballot-native label bitmask; block 0 zeroes the completion counter.
//   (unchanged from the 175 us version)
// ---------------------------------------------------------------------------
__global__ __launch_bounds__(256) void prep_kernel(
    const float* __restrict__ q, const float* __restrict__ p,
    const float* __restrict__ L,
    bf16_t* __restrict__ lqb, bf16_t* __restrict__ pb,
    uint64_t* __restrict__ Lb,
    float* __restrict__ e, float* __restrict__ kld,
    float* __restrict__ CS, float* __restrict__ CL, float* __restrict__ EL,
    int* __restrict__ done)
{
    const int row = blockIdx.x;
    const int t   = threadIdx.x;
    const int wv  = t >> 6, ln = t & 63;

    const float4* q4 = (const float4*)(q + (size_t)row * DDIM);
    const float4* p4 = (const float4*)(p + (size_t)row * DDIM);
    float4 qv = q4[t];
    float4 pv = p4[t];

    float lq0 = __logf(qv.x), lq1 = __logf(qv.y), lq2 = __logf(qv.z), lq3 = __logf(qv.w);
    float lp0 = __logf(pv.x), lp1 = __logf(pv.y), lp2 = __logf(pv.z), lp3 = __logf(pv.w);

    float esum = pv.x * lp0 + pv.y * lp1 + pv.z * lp2 + pv.w * lp3;
    float ksum = pv.x * (lp0 - lq0) + pv.y * (lp1 - lq1)
               + pv.z * (lp2 - lq2) + pv.w * (lp3 - lq3);

    ushort4 uq, up;
    uq.x = f2bf_bits(lq0); uq.y = f2bf_bits(lq1); uq.z = f2bf_bits(lq2); uq.w = f2bf_bits(lq3);
    up.x = f2bf_bits(pv.x); up.y = f2bf_bits(pv.y); up.z = f2bf_bits(pv.z); up.w = f2bf_bits(pv.w);
    ((ushort4*)(lqb + (size_t)row * DDIM))[t] = uq;
    ((ushort4*)(pb  + (size_t)row * DDIM))[t] = up;

    const float4* L4 = (const float4*)(L + (size_t)row * BROWS);
    #pragma unroll
    for (int s = 0; s < 4; s++) {
        float4 lv = L4[s * 256 + t];
        unsigned long long b0 = __ballot(lv.x != 0.0f);
        unsigned long long b1 = __ballot(lv.y != 0.0f);
        unsigned long long b2 = __ballot(lv.z != 0.0f);
        unsigned long long b3 = __ballot(lv.w != 0.0f);
        if (ln < 4) {
            unsigned long long w = (ln == 0) ? b0 : (ln == 1) ? b1 : (ln == 2) ? b2 : b3;
            Lb[(size_t)row * 64 + (s * 4 + wv) * 4 + ln] = w;
        }
    }

    if (t == 0) { CS[row] = 0.f; CL[row] = 0.f; EL[row] = 0.f; }
    if (row == 0 && t == 0) *done = 0;

    #pragma unroll
    for (int off = 32; off > 0; off >>= 1) {
        esum += __shfl_down(esum, off);
        ksum += __shfl_down(ksum, off);
    }
    __shared__ float se[4], sk[4];
    if (ln == 0) { se[wv] = esum; sk[wv] = ksum; }
    __syncthreads();
    if (t == 0) {
        e[row]   = se[0] + se[1] + se[2] + se[3];
        kld[row] = (sk[0] + sk[1] + sk[2] + sk[3]) * (1.0f / DDIM);
    }
}

// ---------------------------------------------------------------------------
// Kernel 2: cross = log_q @ p^T — m97 structure: 128x128 tile, 4 waves (2x2),
//   BK=64, global_load_lds dwordx4 direct staging into LINEAR LDS [128][64]
//   with rule-21 both-sides XOR swizzle (pre-swizzled global source + XOR'd
//   ds_read byte offset, byte ^= (row&7)<<4) -> conflict-free reads.
//   Epilogue + fused final identical in logic to the 175us version, re-indexed.
// ---------------------------------------------------------------------------
__global__ __launch_bounds__(256) void gemm_epi_kernel(
    const bf16_t* __restrict__ Abf,   // log_q [B,D]
    const bf16_t* __restrict__ Bbf,   // p     [B,D]
    const uint64_t* __restrict__ Lb,  // [B,64] ballot-native bitmask
    const float*  __restrict__ e,     // [B]
    const float*  __restrict__ kld,   // [B]
    float* __restrict__ CS, float* __restrict__ CL, float* __restrict__ EL,
    int* __restrict__ done, float* __restrict__ out)
{
    __shared__ __align__(16) bf16_t As[128 * 64];   // 16 KB, linear row-major
    __shared__ __align__(16) bf16_t Bs[128 * 64];   // 16 KB

    const int t     = threadIdx.x;     // 0..255
    const int b     = blockIdx.x;
    // bijective XCD-chunked swizzle: 1024 blocks = 32x32 tiles, 128 tiles/XCD
    const int xcd   = b & 7;
    const int s     = b >> 3;                       // 0..127
    const int i_idx = (xcd >> 2) * 16 + (s >> 3);   // 0..31
    const int j_idx = (xcd & 3) * 8 + (s & 7);      // 0..31
    const int i0    = i_idx * 128;
    const int j0    = j_idx * 128;
    const int wave  = t >> 6;          // 0..3
    const int lane  = t & 63;
    const int q4    = lane >> 4;
    const int ln    = lane & 15;
    const int wrow  = wave & 1;        // 2x2 waves, 64x64 output each
    const int wcol  = wave >> 1;

    f32x4 acc[4][4];
    #pragma unroll
    for (int a = 0; a < 4; a++)
        #pragma unroll
        for (int bq = 0; bq < 4; bq++)
            acc[a][bq] = (f32x4){0.f, 0.f, 0.f, 0.f};

    // staging addresses: thread id covers (row = id>>3, 16B slot = id&7) of the
    // [128][64] bf16 tile; LDS dest is LINEAR (id*16 bytes) as global_load_lds
    // requires; the global SOURCE column is pre-XOR-swizzled so that a reader
    // applying byte ^= (row&7)<<4 gets the right data (involution, rule 21).
    const bf16_t* gA[4]; const bf16_t* gB[4];
    char* lA[4]; char* lB[4];
    #pragma unroll
    for (int n = 0; n < 4; n++) {
        const int id   = t + n * 256;
        const int row  = id >> 3;
        const int gcol = ((id & 7) ^ (row & 7)) * 8;   // pre-swizzled source
        gA[n] = Abf + (size_t)(i0 + row) * DDIM + gcol;
        gB[n] = Bbf + (size_t)(j0 + row) * DDIM + gcol;
        lA[n] = (char*)As + id * 16;
        lB[n] = (char*)Bs + id * 16;
    }

    const int swz = (ln & 7) << 4;     // read-side XOR (row&7 == ln&7 here)

    #pragma unroll 1
    for (int c = 0; c < DDIM / 64; ++c) {
        __syncthreads();               // previous tile's reads done
        #pragma unroll
        for (int n = 0; n < 4; n++) gload16(gA[n] + c * 64, lA[n]);
        #pragma unroll
        for (int n = 0; n < 4; n++) gload16(gB[n] + c * 64, lB[n]);
        __asm__ volatile("s_waitcnt vmcnt(0)" ::: "memory");
        __syncthreads();               // tile resident

        #pragma unroll
        for (int ks = 0; ks < 2; ks++) {
            const int cb = (ks * 64 + q4 * 16) ^ swz;   // swizzled col byte
            bf16x8 af[4], bfr[4];
            #pragma unroll
            for (int mi = 0; mi < 4; mi++)
                af[mi] = *(const bf16x8*)((const char*)As
                           + (wrow * 64 + mi * 16 + ln) * 128 + cb);
            #pragma unroll
            for (int ni = 0; ni < 4; ni++)
                bfr[ni] = *(const bf16x8*)((const char*)Bs
                           + (wcol * 64 + ni * 16 + ln) * 128 + cb);
            #pragma unroll
            for (int mi = 0; mi < 4; mi++)
                #pragma unroll
                for (int ni = 0; ni < 4; ni++)
                    acc[mi][ni] = __builtin_amdgcn_mfma_f32_16x16x32_bf16(
                        af[mi], bfr[ni], acc[mi][ni], 0, 0, 0);
        }
    }

    // ---- epilogue: C/D col = lane&15 (=j), row = quad*4+reg (=i) ----
    const int i_base = i0 + wrow * 64;
    const int j_base = j0 + wcol * 64;
    const int wbase  = (j_base >> 8) * 4 + (ln & 3);
    const int bshift = ((j_base & 255) >> 2) + (ln >> 2);

    float e_j[4];
    #pragma unroll
    for (int ni = 0; ni < 4; ni++) e_j[ni] = e[j_base + ni * 16 + ln];

    #pragma unroll
    for (int mi = 0; mi < 4; mi++) {
        #pragma unroll
        for (int r = 0; r < 4; r++) {
            const int i = i_base + mi * 16 + q4 * 4 + r;
            const uint64_t m  = Lb[(size_t)i * 64 + wbase];
            const uint64_t ms = m >> bshift;
            float cs = 0.f, cl = 0.f, el = 0.f;
            #pragma unroll
            for (int ni = 0; ni < 4; ni++) {
                float cv = acc[mi][ni][r];
                cs += cv;
                if ((ms >> (ni * 4)) & 1ull) { cl += cv; el += e_j[ni]; }
            }
            #pragma unroll
            for (int sft = 1; sft < 16; sft <<= 1) {
                cs += __shfl_xor(cs, sft);
                cl += __shfl_xor(cl, sft);
                el += __shfl_xor(el, sft);
            }
            if (ln == 0) {
                atomicAdd(&CS[i], cs);
                atomicAdd(&CL[i], cl);
                atomicAdd(&EL[i], el);
            }
        }
    }

    // ---- fused final: device-scope atomics are the coherent point; each
    // block's adds drain (vmcnt(0)) before its done-increment ----
    __asm__ volatile("s_waitcnt vmcnt(0)" ::: "memory");
    __syncthreads();
    __shared__ int sIsLast;
    if (t == 0) sIsLast = (atomicAdd(done, 1) == GEMM_BLOCKS - 1) ? 1 : 0;
    __syncthreads();
    if (sIsLast) {
        __shared__ float sred[4];
        __shared__ float sEtot;
        const int wv = t >> 6;

        float ssum = 0.f;
        #pragma unroll
        for (int j = t; j < BROWS; j += 256) ssum += e[j];
        #pragma unroll
        for (int off = 32; off > 0; off >>= 1) ssum += __shfl_down(ssum, off);
        if (lane == 0) sred[wv] = ssum;
        __syncthreads();
        if (t == 0) {
            float a = 0.f;
            #pragma unroll
            for (int k = 0; k < 4; k++) a += sred[k];
            sEtot = a;
        }
        __syncthreads();
        const float Etot = sEtot;
        const float invD = 1.0f / DDIM;

        float rs = 0.f;
        #pragma unroll
        for (int i = t; i < BROWS; i += 256) {
            float el = __hip_atomic_load(&EL[i], __ATOMIC_RELAXED, __HIP_MEMORY_SCOPE_AGENT);
            float cl = __hip_atomic_load(&CL[i], __ATOMIC_RELAXED, __HIP_MEMORY_SCOPE_AGENT);
            float cs = __hip_atomic_load(&CS[i], __ATOMIC_RELAXED, __HIP_MEMORY_SCOPE_AGENT);
            float pos = kld[i] + (el - cl) * invD;
            float neg = (Etot - el - cs + cl) * invD;
            rs += pos / neg;
        }
        __syncthreads();
        #pragma unroll
        for (int off = 32; off > 0; off >>= 1) rs += __shfl_down(rs, off);
        if (lane == 0) sred[wv] = rs;
        __syncthreads();
        if (t == 0) {
            float a = 0.f;
            #pragma unroll
            for (int k = 0; k < 4; k++) a += sred[k];
            out[0] = a;
        }
    }
}

// ---------------------------------------------------------------------------
extern "C" void kernel_launch(void* const* d_in, const int* in_sizes, int n_in,
                              void* d_out, int out_size, void* d_ws, size_t ws_size,
                              hipStream_t stream)
{
    const float* q = (const float*)d_in[0];
    const float* p = (const float*)d_in[1];
    const float* L = (const float*)d_in[2];
    float* out = (float*)d_out;

    char* ws = (char*)d_ws;
    bf16_t* lqb = (bf16_t*)ws;                                    // 8 MB
    bf16_t* pb  = (bf16_t*)(ws + (size_t)BROWS * DDIM * 2);       // 8 MB
    float*  e   = (float*)(ws + (size_t)BROWS * DDIM * 4);        // 16 KB
    float*  kld = e + BROWS;
    float*  CS  = kld + BROWS;
    float*  CL  = CS + BROWS;
    float*  EL  = CL + BROWS;
    uint64_t* Lb = (uint64_t*)(EL + BROWS);                       // 2 MB
    int*    done = (int*)(Lb + (size_t)BROWS * 64);

    prep_kernel<<<BROWS, 256, 0, stream>>>(q, p, L, lqb, pb, Lb, e, kld, CS, CL, EL, done);

    gemm_epi_kernel<<<GEMM_BLOCKS, 256, 0, stream>>>(lqb, pb, Lb, e, kld,
                                                     CS, CL, EL, done, out);
}

// Round 2
// 176.226 us; speedup vs baseline: 1.1175x; 1.1175x over previous
//
#include <hip/hip_runtime.h>
#include <hip/hip_bf16.h>
#include <stdint.h>

#define BROWS 4096
#define DDIM  1024

typedef __bf16 bf16_t;
typedef __bf16 bf16x8 __attribute__((ext_vector_type(8)));
typedef float  f32x4  __attribute__((ext_vector_type(4)));
typedef unsigned int u32;

#define GEMM_BLOCKS 256    // (4096/256)^2 tiles
#define NT  16             // K-tiles of BK=64
#define NIT 8              // main-loop iterations (2 K-tiles each)

// Lb bit layout (ballot-native): word w = (j>>8)*4 + (j&3), bit b = (j&255)>>2.

__device__ __forceinline__ unsigned short f2bf_bits(float f) {
    union { float f; unsigned int u; } v; v.f = f;
    unsigned int u = v.u;
    unsigned int r = (u + 0x7fffu + ((u >> 16) & 1u)) >> 16;
    return (unsigned short)r;
}

__device__ __forceinline__ void gload16(const void* g, void* l) {
    __builtin_amdgcn_global_load_lds(
        (const __attribute__((address_space(1))) u32*)g,
        (__attribute__((address_space(3))) u32*)l, 16, 0, 0);
}

// ---------------------------------------------------------------------------
// Kernel 1: prep — unchanged from the 175us version.
// ---------------------------------------------------------------------------
__global__ __launch_bounds__(256) void prep_kernel(
    const float* __restrict__ q, const float* __restrict__ p,
    const float* __restrict__ L,
    bf16_t* __restrict__ lqb, bf16_t* __restrict__ pb,
    uint64_t* __restrict__ Lb,
    float* __restrict__ e, float* __restrict__ kld,
    float* __restrict__ CS, float* __restrict__ CL, float* __restrict__ EL,
    int* __restrict__ done)
{
    const int row = blockIdx.x;
    const int t   = threadIdx.x;
    const int wv  = t >> 6, ln = t & 63;

    const float4* q4 = (const float4*)(q + (size_t)row * DDIM);
    const float4* p4 = (const float4*)(p + (size_t)row * DDIM);
    float4 qv = q4[t];
    float4 pv = p4[t];

    float lq0 = __logf(qv.x), lq1 = __logf(qv.y), lq2 = __logf(qv.z), lq3 = __logf(qv.w);
    float lp0 = __logf(pv.x), lp1 = __logf(pv.y), lp2 = __logf(pv.z), lp3 = __logf(pv.w);

    float esum = pv.x * lp0 + pv.y * lp1 + pv.z * lp2 + pv.w * lp3;
    float ksum = pv.x * (lp0 - lq0) + pv.y * (lp1 - lq1)
               + pv.z * (lp2 - lq2) + pv.w * (lp3 - lq3);

    ushort4 uq, up;
    uq.x = f2bf_bits(lq0); uq.y = f2bf_bits(lq1); uq.z = f2bf_bits(lq2); uq.w = f2bf_bits(lq3);
    up.x = f2bf_bits(pv.x); up.y = f2bf_bits(pv.y); up.z = f2bf_bits(pv.z); up.w = f2bf_bits(pv.w);
    ((ushort4*)(lqb + (size_t)row * DDIM))[t] = uq;
    ((ushort4*)(pb  + (size_t)row * DDIM))[t] = up;

    const float4* L4 = (const float4*)(L + (size_t)row * BROWS);
    #pragma unroll
    for (int s = 0; s < 4; s++) {
        float4 lv = L4[s * 256 + t];
        unsigned long long b0 = __ballot(lv.x != 0.0f);
        unsigned long long b1 = __ballot(lv.y != 0.0f);
        unsigned long long b2 = __ballot(lv.z != 0.0f);
        unsigned long long b3 = __ballot(lv.w != 0.0f);
        if (ln < 4) {
            unsigned long long w = (ln == 0) ? b0 : (ln == 1) ? b1 : (ln == 2) ? b2 : b3;
            Lb[(size_t)row * 64 + (s * 4 + wv) * 4 + ln] = w;
        }
    }

    if (t == 0) { CS[row] = 0.f; CL[row] = 0.f; EL[row] = 0.f; }
    if (row == 0 && t == 0) *done = 0;

    #pragma unroll
    for (int off = 32; off > 0; off >>= 1) {
        esum += __shfl_down(esum, off);
        ksum += __shfl_down(ksum, off);
    }
    __shared__ float se[4], sk[4];
    if (ln == 0) { se[wv] = esum; sk[wv] = ksum; }
    __syncthreads();
    if (t == 0) {
        e[row]   = se[0] + se[1] + se[2] + se[3];
        kld[row] = (sk[0] + sk[1] + sk[2] + sk[3]) * (1.0f / DDIM);
    }
}

// ---------------------------------------------------------------------------
// Kernel 2: 256x256 8-phase GEMM (T3+T4 counted vmcnt, T5 setprio, T2 swizzle)
// ---------------------------------------------------------------------------

#define VM4 __asm__ volatile("s_waitcnt vmcnt(4)" ::: "memory")
#define VM0 __asm__ volatile("s_waitcnt vmcnt(0)" ::: "memory")
#define NOP ((void)0)

// stage one half-tile (256 rows x 32 cols bf16 = 16KB, 2 gloads/thread)
#define STAGE_A(KT, KH) do { \
    const int _ko = (KT) * 64 + (KH) * 32; \
    char* _r = (char*)As + ((((KT) & 1) * 2 + (KH)) * 16384); \
    gload16(gA0 + _ko, _r + dst0); \
    gload16(gA1 + _ko, _r + dst1); \
} while (0)

#define STAGE_B(KT, KH) do { \
    const int _ko = (KT) * 64 + (KH) * 32; \
    char* _r = (char*)Bs + ((((KT) & 1) * 2 + (KH)) * 16384); \
    gload16(gB0 + _ko, _r + dst0); \
    gload16(gB1 + _ko, _r + dst1); \
} while (0)

// one phase: ds_reads + stage-issue | barrier | 16 MFMA | (vmcnt) barrier
#define PHASE(DB, KH, FMB, LOADB, STG, WAITS) do { \
    const char* _Ar = (const char*)As + (((DB) * 2 + (KH)) * 16384); \
    const char* _Br = (const char*)Bs + (((DB) * 2 + (KH)) * 16384); \
    bf16x8 _af[4]; \
    _Pragma("unroll") \
    for (int _f = 0; _f < 4; ++_f) \
        _af[_f] = *(const bf16x8*)(_Ar + aOff + ((FMB) + _f) * 1024); \
    if (LOADB) { \
        _Pragma("unroll") \
        for (int _n = 0; _n < 4; ++_n) \
            bfr[_n] = *(const bf16x8*)(_Br + bOff + _n * 1024); \
    } \
    STG; \
    __asm__ volatile("" ::: "memory"); \
    __builtin_amdgcn_s_barrier(); \
    __builtin_amdgcn_s_setprio(1); \
    _Pragma("unroll") \
    for (int _f = 0; _f < 4; ++_f) \
        _Pragma("unroll") \
        for (int _n = 0; _n < 4; ++_n) \
            acc[(FMB) + _f][_n] = __builtin_amdgcn_mfma_f32_16x16x32_bf16( \
                _af[_f], bfr[_n], acc[(FMB) + _f][_n], 0, 0, 0); \
    __builtin_amdgcn_s_setprio(0); \
    WAITS; \
    __asm__ volatile("" ::: "memory"); \
    __builtin_amdgcn_s_barrier(); \
} while (0)

__global__ __launch_bounds__(512, 2) void gemm_epi_kernel(
    const bf16_t* __restrict__ Abf,   // log_q [B,D]
    const bf16_t* __restrict__ Bbf,   // p     [B,D]
    const uint64_t* __restrict__ Lb,  // [B,64] ballot-native bitmask
    const float*  __restrict__ e,     // [B]
    const float*  __restrict__ kld,   // [B]
    float* __restrict__ CS, float* __restrict__ CL, float* __restrict__ EL,
    int* __restrict__ done, float* __restrict__ out)
{
    // [dbuf][k-half][256 rows][32 cols] bf16, 16KB regions, 64KB each
    __shared__ __align__(16) bf16_t As[2 * 2 * 256 * 32];
    __shared__ __align__(16) bf16_t Bs[2 * 2 * 256 * 32];

    const int t    = threadIdx.x;      // 0..511
    const int b    = blockIdx.x;
    const int xcd  = b & 7;
    const int s    = b >> 3;                       // 0..31
    const int i_idx = (xcd >> 1) * 4 + (s >> 3);   // 0..15
    const int j_idx = (xcd & 1) * 8 + (s & 7);     // 0..15
    const int i0   = i_idx * 256;
    const int j0   = j_idx * 256;
    const int wave = t >> 6;           // 0..7
    const int lane = t & 63;
    const int q4u  = lane >> 4;
    const int ln   = lane & 15;
    const int wm   = wave >> 2;        // 0..1  (M half)
    const int wn   = wave & 3;         // 0..3  (N quarter)

    // ds_read byte offsets within a [256][32] region (64B rows).
    // swizzle: 16B-slot ^= (row>>1)&3  -> 2-way bank aliasing (free).
    const int aRow  = wm * 128 + ln;
    const int aSlot = q4u ^ ((aRow >> 1) & 3);
    const int aOff  = aRow * 64 + aSlot * 16;
    const int bRow  = wn * 64 + ln;
    const int bSlot = q4u ^ ((bRow >> 1) & 3);
    const int bOff  = bRow * 64 + bSlot * 16;

    // staging: thread covers (row = id>>2, slot = id&3) of [256][32];
    // LDS dest linear (id*16B); global source slot pre-XOR'd (involution).
    const int id20 = t, id21 = t + 512;
    const int row0 = id20 >> 2, row1 = id21 >> 2;
    const int ss0  = (id20 & 3) ^ ((row0 >> 1) & 3);
    const int ss1  = (id21 & 3) ^ ((row1 >> 1) & 3);
    const bf16_t* gA0 = Abf + (size_t)(i0 + row0) * DDIM + ss0 * 8;
    const bf16_t* gA1 = Abf + (size_t)(i0 + row1) * DDIM + ss1 * 8;
    const bf16_t* gB0 = Bbf + (size_t)(j0 + row0) * DDIM + ss0 * 8;
    const bf16_t* gB1 = Bbf + (size_t)(j0 + row1) * DDIM + ss1 * 8;
    const int dst0 = id20 * 16, dst1 = id21 * 16;

    f32x4 acc[8][4];
    #pragma unroll
    for (int a = 0; a < 8; a++)
        #pragma unroll
        for (int n = 0; n < 4; n++)
            acc[a][n] = (f32x4){0.f, 0.f, 0.f, 0.f};
    bf16x8 bfr[4];

    // prologue: kt0 fully + kt1 kh0; drain to 4 outstanding (kt0 resident)
    STAGE_A(0, 0); STAGE_B(0, 0);
    STAGE_A(0, 1); STAGE_B(0, 1);
    STAGE_A(1, 0); STAGE_B(1, 0);
    VM4;
    __asm__ volatile("" ::: "memory");
    __builtin_amdgcn_s_barrier();

    #pragma unroll 1
    for (int it = 0; it < NIT - 1; ++it) {
        const int k1 = 2 * it + 1, k2 = 2 * it + 2, k3 = 2 * it + 3;
        PHASE(0, 0, 0, true,  STAGE_A(k1, 1), NOP);
        PHASE(0, 0, 4, false, STAGE_B(k1, 1), NOP);
        PHASE(0, 1, 0, true,  STAGE_A(k2, 0), NOP);
        PHASE(0, 1, 4, false, STAGE_B(k2, 0), VM4);
        PHASE(1, 0, 0, true,  STAGE_A(k2, 1), NOP);
        PHASE(1, 0, 4, false, STAGE_B(k2, 1), NOP);
        PHASE(1, 1, 0, true,  STAGE_A(k3, 0), NOP);
        PHASE(1, 1, 4, false, STAGE_B(k3, 0), VM4);
    }
    // last iteration: only kt15 kh1 remains to stage; full drain at phase 4
    PHASE(0, 0, 0, true,  STAGE_A(15, 1), NOP);
    PHASE(0, 0, 4, false, STAGE_B(15, 1), NOP);
    PHASE(0, 1, 0, true,  NOP, NOP);
    PHASE(0, 1, 4, false, NOP, VM0);
    PHASE(1, 0, 0, true,  NOP, NOP);
    PHASE(1, 0, 4, false, NOP, NOP);
    PHASE(1, 1, 0, true,  NOP, NOP);
    PHASE(1, 1, 4, false, NOP, NOP);

    // ---- epilogue: C/D col = lane&15 (=j), row = quad*4+reg (=i) ----
    const int i_base = i0 + wm * 128;
    const int j_base = j0 + wn * 64;
    const int wbase  = (j_base >> 8) * 4 + (ln & 3);
    const int bshift = ((j_base & 255) >> 2) + (ln >> 2);

    float e_j[4];
    #pragma unroll
    for (int fn = 0; fn < 4; fn++) e_j[fn] = e[j_base + fn * 16 + ln];

    #pragma unroll
    for (int fm = 0; fm < 8; fm++) {
        #pragma unroll
        for (int r = 0; r < 4; r++) {
            const int i = i_base + fm * 16 + q4u * 4 + r;
            const uint64_t m  = Lb[(size_t)i * 64 + wbase];
            const uint64_t ms = m >> bshift;
            float cs = 0.f, cl = 0.f, el = 0.f;
            #pragma unroll
            for (int fn = 0; fn < 4; fn++) {
                float cv = acc[fm][fn][r];
                cs += cv;
                if ((ms >> (fn * 4)) & 1ull) { cl += cv; el += e_j[fn]; }
            }
            #pragma unroll
            for (int sft = 1; sft < 16; sft <<= 1) {
                cs += __shfl_xor(cs, sft);
                cl += __shfl_xor(cl, sft);
                el += __shfl_xor(el, sft);
            }
            if (ln == 0) {
                atomicAdd(&CS[i], cs);
                atomicAdd(&CL[i], cl);
                atomicAdd(&EL[i], el);
            }
        }
    }

    // ---- fused final: device-scope atomics are the coherent point ----
    __asm__ volatile("s_waitcnt vmcnt(0)" ::: "memory");
    __syncthreads();
    __shared__ int sIsLast;
    if (t == 0) sIsLast = (atomicAdd(done, 1) == GEMM_BLOCKS - 1) ? 1 : 0;
    __syncthreads();
    if (sIsLast) {
        __shared__ float sred[8];
        __shared__ float sEtot;
        const int wv8 = t >> 6;

        float ssum = 0.f;
        #pragma unroll
        for (int j = t; j < BROWS; j += 512) ssum += e[j];
        #pragma unroll
        for (int off = 32; off > 0; off >>= 1) ssum += __shfl_down(ssum, off);
        if (lane == 0) sred[wv8] = ssum;
        __syncthreads();
        if (t == 0) {
            float a = 0.f;
            #pragma unroll
            for (int k = 0; k < 8; k++) a += sred[k];
            sEtot = a;
        }
        __syncthreads();
        const float Etot = sEtot;
        const float invD = 1.0f / DDIM;

        float rs = 0.f;
        #pragma unroll
        for (int i = t; i < BROWS; i += 512) {
            float el = __hip_atomic_load(&EL[i], __ATOMIC_RELAXED, __HIP_MEMORY_SCOPE_AGENT);
            float cl = __hip_atomic_load(&CL[i], __ATOMIC_RELAXED, __HIP_MEMORY_SCOPE_AGENT);
            float cs = __hip_atomic_load(&CS[i], __ATOMIC_RELAXED, __HIP_MEMORY_SCOPE_AGENT);
            float pos = kld[i] + (el - cl) * invD;
            float neg = (Etot - el - cs + cl) * invD;
            rs += pos / neg;
        }
        __syncthreads();
        #pragma unroll
        for (int off = 32; off > 0; off >>= 1) rs += __shfl_down(rs, off);
        if (lane == 0) sred[wv8] = rs;
        __syncthreads();
        if (t == 0) {
            float a = 0.f;
            #pragma unroll
            for (int k = 0; k < 8; k++) a += sred[k];
            out[0] = a;
        }
    }
}

// ---------------------------------------------------------------------------
extern "C" void kernel_launch(void* const* d_in, const int* in_sizes, int n_in,
                              void* d_out, int out_size, void* d_ws, size_t ws_size,
                              hipStream_t stream)
{
    const float* q = (const float*)d_in[0];
    const float* p = (const float*)d_in[1];
    const float* L = (const float*)d_in[2];
    float* out = (float*)d_out;

    char* ws = (char*)d_ws;
    bf16_t* lqb = (bf16_t*)ws;                                    // 8 MB
    bf16_t* pb  = (bf16_t*)(ws + (size_t)BROWS * DDIM * 2);       // 8 MB
    float*  e   = (float*)(ws + (size_t)BROWS * DDIM * 4);        // 16 KB
    float*  kld = e + BROWS;
    float*  CS  = kld + BROWS;
    float*  CL  = CS + BROWS;
    float*  EL  = CL + BROWS;
    uint64_t* Lb = (uint64_t*)(EL + BROWS);                       // 2 MB
    int*    done = (int*)(Lb + (size_t)BROWS * 64);

    prep_kernel<<<BROWS, 256, 0, stream>>>(q, p, L, lqb, pb, Lb, e, kld, CS, CL, EL, done);

    gemm_epi_kernel<<<GEMM_BLOCKS, 512, 0, stream>>>(lqb, pb, Lb, e, kld,
                                                     CS, CL, EL, done, out);
}